// Round 16
// baseline (265.121 us; speedup 1.0000x reference)
//
#include <hip/hip_runtime.h>
#include <hip/hip_bf16.h>

// ---------- types & helpers ----------
typedef __attribute__((ext_vector_type(4))) float  f32x4;
typedef __attribute__((ext_vector_type(8))) __bf16 bf16x8;
typedef __attribute__((ext_vector_type(8))) unsigned short u16x8;

typedef const __attribute__((address_space(1))) void gas_void;
typedef __attribute__((address_space(3))) void las_void;

__device__ __forceinline__ unsigned short f2bf(float x) {
    unsigned u = __builtin_bit_cast(unsigned, x);
    u += 0x7fffu + ((u >> 16) & 1u);          // round-to-nearest-even
    return (unsigned short)(u >> 16);
}
__device__ __forceinline__ float bf2f(unsigned short h) {
    unsigned u = ((unsigned)h) << 16;
    return __builtin_bit_cast(float, u);
}
__device__ __forceinline__ void gload_lds16(const void* g, void* l) {
    __builtin_amdgcn_global_load_lds((gas_void*)g, (las_void*)l, 16, 0, 0);
}

#define WAITVM(N) asm volatile("s_waitcnt vmcnt(" #N ")" ::: "memory")
#define BAR() do { __builtin_amdgcn_s_barrier(); __builtin_amdgcn_sched_barrier(0); } while (0)

// ---------- kernel 1: fp32 -> bf16 convert (vectorized) ----------
__global__ void k_f32_to_bf16(const float* __restrict__ in,
                              unsigned short* __restrict__ out, int n4) {
    int i = blockIdx.x * blockDim.x + threadIdx.x;
    if (i < n4) {
        float4 v = ((const float4*)in)[i];
        ushort4 o;
        o.x = f2bf(v.x); o.y = f2bf(v.y); o.z = f2bf(v.z); o.w = f2bf(v.w);
        ((ushort4*)out)[i] = o;
    }
}

// ---------- kernel 2: W [K=1024][N=3072] fp32 -> Wt [N][K] bf16 ----------
__global__ void k_transpose_w(const float* __restrict__ W,
                              unsigned short* __restrict__ Wt,
                              int K, int N) {
    __shared__ unsigned short tile[32][33];
    int n0 = blockIdx.x * 32, k0 = blockIdx.y * 32;
    int tx = threadIdx.x, ty = threadIdx.y;   // 32 x 8
#pragma unroll
    for (int i = 0; i < 4; i++) {
        int kk = ty + i * 8;
        tile[kk][tx] = f2bf(W[(size_t)(k0 + kk) * N + n0 + tx]);
    }
    __syncthreads();
#pragma unroll
    for (int i = 0; i < 4; i++) {
        int nn = ty + i * 8;
        Wt[(size_t)(n0 + nn) * K + k0 + tx] = tile[tx][nn];
    }
}

// ============================================================================
// GEMM1: 128x128 tile, BK=64, 4 waves, 256 thr, 2-phase (R9/R10-verified).
// L2-hot operands; ~1.3 PF measured.  UNCHANGED.
// ============================================================================
__global__ __launch_bounds__(256, 2) void k_g128qkv(
        const unsigned short* __restrict__ A, int lda,
        const unsigned short* __restrict__ Bt, int ldb,
        unsigned short* __restrict__ C,
        unsigned short* __restrict__ Vt,
        const float* __restrict__ bias, int K) {
    __shared__ __align__(16) unsigned short As[2][8192];   // 128x64
    __shared__ __align__(16) unsigned short Bs[2][8192];   // 128x64

    const int nwg  = gridDim.x * gridDim.y;
    const int flat = blockIdx.y * gridDim.x + blockIdx.x;
    const int swzb = (flat & 7) * (nwg >> 3) + (flat >> 3);
    const int m0   = (swzb / gridDim.x) * 128;
    const int n0   = (swzb % gridDim.x) * 128;

    const int tid  = threadIdx.x;
    const int lane = tid & 63;
    const int wid  = tid >> 6;      // 0..3
    const int wr   = wid >> 1;
    const int wc   = wid & 1;
    const int l15  = lane & 15;
    const int l4   = lane >> 4;

    f32x4 acc[4][4] = {};

    const int srow = tid >> 3;                              // 0..31
    const int kel  = (((lane & 7) ^ (lane >> 3)) << 3);
    const int c0 = (l4 << 4) ^ ((l15 & 7) << 4);
    const int c1 = (64 + (l4 << 4)) ^ ((l15 & 7) << 4);

    auto stA = [&](int b, int g, int kt) {
        gload_lds16(A + (size_t)(m0 + g * 32 + srow) * lda + kt * 64 + kel,
                    (char*)As + b * 16384 + g * 4096 + (wid << 10));
    };
    auto stB = [&](int b, int g, int kt) {
        gload_lds16(Bt + (size_t)(n0 + g * 32 + srow) * ldb + kt * 64 + kel,
                    (char*)Bs + b * 16384 + g * 4096 + (wid << 10));
    };

#define MM(I, J, X, Y) \
    acc[I][J] = __builtin_amdgcn_mfma_f32_16x16x32_bf16((X), (Y), acc[I][J], 0, 0, 0)

    const int NT = K >> 6;
    stA(0, 0, 0); stA(0, 1, 0); stA(0, 2, 0); stA(0, 3, 0);
    stB(0, 0, 0); stB(0, 1, 0); stB(0, 2, 0); stB(0, 3, 0);

    for (int t = 0; t < NT; t++) {
        const int cur = t & 1, nxt = cur ^ 1;
        const char* Ab = (const char*)As + cur * 16384;
        const char* Bb = (const char*)Bs + cur * 16384;
        const bool hn = (t + 1 < NT);

        bf16x8 af[4], bq[4];

        if (hn) {
            stA(nxt, 0, t + 1); stA(nxt, 1, t + 1); stA(nxt, 2, t + 1); stA(nxt, 3, t + 1);
            WAITVM(4);
        } else {
            WAITVM(0);
        }
        BAR();
#pragma unroll
        for (int mf = 0; mf < 4; mf++)
            af[mf] = *(const bf16x8*)(Ab + (wr * 64 + mf * 16 + l15) * 128 + c0);
#pragma unroll
        for (int nf = 0; nf < 4; nf++)
            bq[nf] = *(const bf16x8*)(Bb + (wc * 64 + nf * 16 + l15) * 128 + c0);
        __builtin_amdgcn_s_setprio(1);
#pragma unroll
        for (int mf = 0; mf < 4; mf++)
#pragma unroll
        for (int nf = 0; nf < 4; nf++)
            MM(mf, nf, af[mf], bq[nf]);
        __builtin_amdgcn_s_setprio(0);

        if (hn) {
            stB(nxt, 0, t + 1); stB(nxt, 1, t + 1); stB(nxt, 2, t + 1); stB(nxt, 3, t + 1);
        }
#pragma unroll
        for (int mf = 0; mf < 4; mf++)
            af[mf] = *(const bf16x8*)(Ab + (wr * 64 + mf * 16 + l15) * 128 + c1);
#pragma unroll
        for (int nf = 0; nf < 4; nf++)
            bq[nf] = *(const bf16x8*)(Bb + (wc * 64 + nf * 16 + l15) * 128 + c1);
        __builtin_amdgcn_s_setprio(1);
#pragma unroll
        for (int mf = 0; mf < 4; mf++)
#pragma unroll
        for (int nf = 0; nf < 4; nf++)
            MM(mf, nf, af[mf], bq[nf]);
        __builtin_amdgcn_s_setprio(0);
        BAR();
    }
#undef MM

#pragma unroll
    for (int mf = 0; mf < 4; mf++) {
        const int row = m0 + wr * 64 + mf * 16 + l4 * 4;
#pragma unroll
        for (int nf = 0; nf < 4; nf++) {
            const int col = n0 + wc * 64 + nf * 16 + l15;
            const f32x4 av = acc[mf][nf];
            const float bv = bias[col];
            const int lc = col & 1023;
            if (col < 2048) {
#pragma unroll
                for (int r = 0; r < 4; r++)
                    C[(size_t)(col >> 10) * 8388608 +
                      (size_t)(row + r) * 1024 + lc] = f2bf(av[r] + bv);
            } else {
                const int b = row >> 12, s = row & 4095;
                ushort4 o;
                o.x = f2bf(av[0] + bv); o.y = f2bf(av[1] + bv);
                o.z = f2bf(av[2] + bv); o.w = f2bf(av[3] + bv);
                *(ushort4*)&Vt[(size_t)b * 4194304 + (size_t)lc * 4096 + s] = o;
            }
        }
    }
}

// ============================================================================
// SCORES R16: cross-block-TLP isolation.  256x128 tile (M=Q-rows, N=K-rows),
// BK=32, 4 waves (2M x 2N, per-wave 128x64), 256 thr, LDS 48 KB -> exactly
// 2 INDEPENDENT blocks/CU (acc 128 AGPR + ~60 arch = 188 <= 256 regs/wave at
// 2 waves/SIMD).  This is GEMM1's winning configuration (the only plateaued-
// kernel structural difference) applied to scores with matched reg budget —
// the isolation R14 muddied (it changed tile+rounds+fetch at once).
// Ledger (6 stage instrs/tile: A x4, B x2, deep slack): issue tile t+1's 6 at
// P1 top -> outstanding 12; WAITVM(6) retires exactly tile t (FIFO); last 0.
// BK32 swizzle (64-B rows, 4 slots; R14-verified): phys slot s of row r holds
// logical chunk s^(r&3); stage kel = ((tid&3)^((tid>>2)&3))*8; read slot
// l4^(l15&3) -> 2-way banks = free.
// Single MFMA cluster/tile: 12 ds_read_b128 + 32 MFMA between 2 barriers.
// Epilogue: P = exp(s*scale) unnormalized + deterministic per-row partials
// (slot = (n0>>7)*2 + wc, 64 slots/row, each written exactly once).
// ============================================================================
__global__ __launch_bounds__(256, 2) void k_scores(
        const unsigned short* __restrict__ A,
        const unsigned short* __restrict__ Bt,
        unsigned short* __restrict__ C,
        float* __restrict__ part,
        int K, float scale, long sA, long sB, long sC) {
    __shared__ __align__(16) unsigned short As[2][8192];   // 256x32
    __shared__ __align__(16) unsigned short Bs[2][4096];   // 128x32

    const int z = blockIdx.z;
    A  += (size_t)z * sA;
    Bt += (size_t)z * sB;

    // XCD-bijective chunked swizzle (nwg = 512, %8==0)
    const int nwg  = gridDim.x * gridDim.y;
    const int flat = blockIdx.y * gridDim.x + blockIdx.x;
    const int swzb = (flat & 7) * (nwg >> 3) + (flat >> 3);
    const int m0   = (swzb / gridDim.x) * 256;
    const int n0   = (swzb % gridDim.x) * 128;

    const int tid  = threadIdx.x;
    const int lane = tid & 63;
    const int wid  = tid >> 6;      // 0..3
    const int wr   = wid >> 1;      // 0..1 (row half)
    const int wc   = wid & 1;       // 0..1 (col half)
    const int l15  = lane & 15;
    const int l4   = lane >> 4;     // 0..3

    f32x4 acc[8][4] = {};           // 128 AGPR

    // staging (BK=32, 64-B rows): call covers 64 rows (4 thr/row x 16 B)
    const int srow = tid >> 2;                              // 0..63
    const int kel  = (((tid & 3) ^ ((tid >> 2) & 3)) << 3); // swizzled src chunk
    const int csw  = ((l4 ^ (l15 & 3)) << 4);               // read byte slot

    auto stA = [&](int b, int g, int kt) {                  // g = 0..3
        gload_lds16(A + (size_t)(m0 + g * 64 + srow) * 1024 + kt * 32 + kel,
                    (char*)As + b * 16384 + g * 4096 + (wid << 10));
    };
    auto stB = [&](int b, int g, int kt) {                  // g = 0..1
        gload_lds16(Bt + (size_t)(n0 + g * 64 + srow) * 1024 + kt * 32 + kel,
                    (char*)Bs + b * 8192 + g * 4096 + (wid << 10));
    };

#define MM(I, J, X, Y) \
    acc[I][J] = __builtin_amdgcn_mfma_f32_16x16x32_bf16((X), (Y), acc[I][J], 0, 0, 0)

    const int NT = K >> 5;          // BK=32 -> 32 tiles
    stA(0, 0, 0); stA(0, 1, 0); stA(0, 2, 0); stA(0, 3, 0);
    stB(0, 0, 0); stB(0, 1, 0);

    for (int t = 0; t < NT; t++) {
        const int cur = t & 1, nxt = cur ^ 1;
        const char* Ab = (const char*)As + cur * 16384;
        const char* Bb = (const char*)Bs + cur * 8192;
        const bool hn = (t + 1 < NT);

        // stage FULL tile t+1, deep gate
        if (hn) {
            stA(nxt, 0, t + 1); stA(nxt, 1, t + 1); stA(nxt, 2, t + 1); stA(nxt, 3, t + 1);
            stB(nxt, 0, t + 1); stB(nxt, 1, t + 1);
            WAITVM(6);     // outstanding 12 -> retires exactly tile t's 6
        } else {
            WAITVM(0);
        }
        BAR();

        bf16x8 af[8], bq[4];
#pragma unroll
        for (int mf = 0; mf < 8; mf++)
            af[mf] = *(const bf16x8*)(Ab + (wr * 128 + mf * 16 + l15) * 64 + csw);
#pragma unroll
        for (int nf = 0; nf < 4; nf++)
            bq[nf] = *(const bf16x8*)(Bb + (wc * 64 + nf * 16 + l15) * 64 + csw);
        __builtin_amdgcn_s_setprio(1);
#pragma unroll
        for (int mf = 0; mf < 8; mf++)
#pragma unroll
        for (int nf = 0; nf < 4; nf++)
            MM(mf, nf, af[mf], bq[nf]);
        __builtin_amdgcn_s_setprio(0);
        BAR();
    }
#undef MM

    // ---- epilogue: exp + write P_unnorm + per-row partial sums ----
    const int slot = ((n0 >> 7) << 1) + wc;    // 0..63
#pragma unroll
    for (int mf = 0; mf < 8; mf++) {
        const int row = m0 + wr * 128 + mf * 16 + l4 * 4;
        float rs[4] = {0.f, 0.f, 0.f, 0.f};
#pragma unroll
        for (int nf = 0; nf < 4; nf++) {
            const int col = n0 + wc * 64 + nf * 16 + l15;
            const f32x4 av = acc[mf][nf];
#pragma unroll
            for (int r = 0; r < 4; r++) {
                const float e = __expf(av[r] * scale);
                rs[r] += e;
                C[(size_t)z * sC + (size_t)(row + r) * 4096 + col] = f2bf(e);
            }
        }
#pragma unroll
        for (int r = 0; r < 4; r++) {
#pragma unroll
            for (int o = 1; o < 16; o <<= 1)
                rs[r] += __shfl_xor(rs[r], o);
        }
        if (l15 == 0) {
#pragma unroll
            for (int r = 0; r < 4; r++)
                part[((size_t)z * 4096 + row + r) * 64 + slot] = rs[r];
        }
    }
}

// ---------- reduce 64 partials -> rinv = 1/rowsum ----------
__global__ __launch_bounds__(256) void k_rinv(const float* __restrict__ part,
                                              float* __restrict__ rinv, int nrows) {
    int row = blockIdx.x * blockDim.x + threadIdx.x;
    if (row < nrows) {
        const float* p = part + (size_t)row * 64;
        float s = 0.f;
#pragma unroll
        for (int i = 0; i < 16; i++) {
            f32x4 v = *(const f32x4*)(p + i * 4);
            s += v[0] + v[1] + v[2] + v[3];
        }
        rinv[row] = 1.0f / s;
    }
}

// ============================================================================
// PV: 256x128 tile, BK=64, 8 waves (2M x 4N), 512 thr, 2-phase + deep-slack
// staging (R12-best, reproduced R15).  UNCHANGED.
// ============================================================================
__global__ __launch_bounds__(512, 2) void k_pv256(
        const unsigned short* __restrict__ A,
        const unsigned short* __restrict__ Bt,
        float* __restrict__ C,
        const float* __restrict__ rinv,
        int K, long sA, long sB, long sC) {
    __shared__ __align__(16) unsigned short As[2][16384];   // 256x64
    __shared__ __align__(16) unsigned short Bs[2][8192];    // 128x64

    const int z = blockIdx.z;
    A  += (size_t)z * sA;
    Bt += (size_t)z * sB;

    const int nwg  = gridDim.x * gridDim.y;      // 128
    const int flat = blockIdx.y * gridDim.x + blockIdx.x;
    const int swzb = (flat & 7) * (nwg >> 3) + (flat >> 3);
    const int m0   = (swzb / gridDim.x) * 256;
    const int n0   = (swzb % gridDim.x) * 128;

    const int tid  = threadIdx.x;
    const int lane = tid & 63;
    const int wid  = tid >> 6;
    const int wm   = wid >> 2;
    const int wn   = wid & 3;
    const int l15  = lane & 15;
    const int l4   = lane >> 4;

    f32x4 acc[8][2] = {};

    const int srow = tid >> 3;
    const int kel  = (((lane & 7) ^ (lane >> 3)) << 3);
    const int c0 = ((l4 << 4)) ^ ((l15 & 7) << 4);
    const int c1 = (64 + (l4 << 4)) ^ ((l15 & 7) << 4);

    auto stageA1 = [&](int b, int a, int kt) {
        const int r = a * 64 + srow;
        gload_lds16(A + (size_t)(m0 + r) * 4096 + kt * 64 + kel,
                    (char*)As + b * 32768 + a * 8192 + (wid << 10));
    };
    auto stageB1 = [&](int b, int c, int kt) {
        const int r = c * 64 + srow;
        gload_lds16(Bt + (size_t)(n0 + r) * 4096 + kt * 64 + kel,
                    (char*)Bs + b * 16384 + c * 8192 + (wid << 10));
    };

#define MM(I, J, X, Y) \
    acc[I][J] = __builtin_amdgcn_mfma_f32_16x16x32_bf16((X), (Y), acc[I][J], 0, 0, 0)

    const int NT = K >> 6;
    stageA1(0, 0, 0); stageA1(0, 1, 0); stageA1(0, 2, 0); stageA1(0, 3, 0);
    stageB1(0, 0, 0); stageB1(0, 1, 0);

    for (int t = 0; t < NT; t++) {
        const int cur = t & 1, nxt = cur ^ 1;
        const char* Ab = (const char*)As + cur * 32768;
        const char* Bb = (const char*)Bs + cur * 16384;

        // ---------- P1: stage FULL tile t+1, deep gate ----------
        if (t + 1 < NT) {
            stageA1(nxt, 0, t + 1); stageA1(nxt, 1, t + 1);
            stageA1(nxt, 2, t + 1); stageA1(nxt, 3, t + 1);
            stageB1(nxt, 0, t + 1); stageB1(nxt, 1, t + 1);
            WAITVM(6);     // outstanding 12 -> retires exactly tile t's 6
        } else {
            WAITVM(0);
        }
        BAR();

        bf16x8 bfrg[2][2];
#pragma unroll
        for (int nf = 0; nf < 2; nf++) {
            const int rb = (wn * 32 + nf * 16 + l15) * 128;
            bfrg[nf][0] = *(const bf16x8*)(Bb + rb + c0);
            bfrg[nf][1] = *(const bf16x8*)(Bb + rb + c1);
        }
        {
            bf16x8 af[4][2];
#pragma unroll
            for (int mf = 0; mf < 4; mf++) {
                const int ra = (wm * 128 + 0 * 64 + mf * 16 + l15) * 128;
                af[mf][0] = *(const bf16x8*)(Ab + ra + c0);
                af[mf][1] = *(const bf16x8*)(Ab + ra + c1);
            }
            __builtin_amdgcn_s_setprio(1);
#pragma unroll
            for (int mf = 0; mf < 4; mf++)
#pragma unroll
            for (int nf = 0; nf < 2; nf++) {
                MM(mf, nf, af[mf][0], bfrg[nf][0]);
                MM(mf, nf, af[mf][1], bfrg[nf][1]);
            }
            __builtin_amdgcn_s_setprio(0);
        }

        // ---------- P2 (no staging) ----------
        {
            bf16x8 af[4][2];
#pragma unroll
            for (int mf = 0; mf < 4; mf++) {
                const int ra = (wm * 128 + 1 * 64 + mf * 16 + l15) * 128;
                af[mf][0] = *(const bf16x8*)(Ab + ra + c0);
                af[mf][1] = *(const bf16x8*)(Ab + ra + c1);
            }
            __builtin_amdgcn_s_setprio(1);
#pragma unroll
            for (int mf = 0; mf < 4; mf++)
#pragma unroll
            for (int nf = 0; nf < 2; nf++) {
                MM(4 + mf, nf, af[mf][0], bfrg[nf][0]);
                MM(4 + mf, nf, af[mf][1], bfrg[nf][1]);
            }
            __builtin_amdgcn_s_setprio(0);
        }
        __builtin_amdgcn_s_barrier();
        __builtin_amdgcn_sched_barrier(0);
    }
#undef MM

    // epilogue: normalize by rinv[row] and store fp32
#pragma unroll
    for (int qm = 0; qm < 2; qm++)
#pragma unroll
    for (int mf = 0; mf < 4; mf++) {
        const int row = m0 + wm * 128 + qm * 64 + mf * 16 + l4 * 4;
        const f32x4 riv = *(const f32x4*)&rinv[(size_t)z * 4096 + row];
#pragma unroll
        for (int nf = 0; nf < 2; nf++) {
            const int col = n0 + wn * 32 + nf * 16 + l15;
            const f32x4 av = acc[qm * 4 + mf][nf];
#pragma unroll
            for (int r = 0; r < 4; r++)
                C[(size_t)z * sC + (size_t)(row + r) * 1024 + col] = av[r] * riv[r];
        }
    }
}

// ---------- launch ----------
extern "C" void kernel_launch(void* const* d_in, const int* in_sizes, int n_in,
                              void* d_out, int out_size, void* d_ws, size_t ws_size,
                              hipStream_t stream) {
    const float* x    = (const float*)d_in[0];   // [2,4096,1024]
    const float* W    = (const float*)d_in[1];   // [1024,3072]
    const float* bias = (const float*)d_in[2];   // [3072]
    float* out        = (float*)d_out;           // [2,4096,1024]

    // ws (MB): Qb@0(16) Kb@16(16) Vt@32(16) xb@48(16) Wt@64(6)
    //          Pcat@48(64, overlays dead xb/Wt) part@112(4) rinv@116(32KB)
    char* ws = (char*)d_ws;
    unsigned short* Qb   = (unsigned short*)(ws);
    unsigned short* Vt   = (unsigned short*)(ws + 33554432);
    unsigned short* xb   = (unsigned short*)(ws + 50331648);
    unsigned short* Wt   = (unsigned short*)(ws + 67108864);
    unsigned short* Pcat = (unsigned short*)(ws + 50331648);
    float*          part = (float*)(ws + 117440512);
    float*          rinv = (float*)(ws + 121634816);

    // 1. x -> bf16
    k_f32_to_bf16<<<8192, 256, 0, stream>>>(x, xb, (8192 * 1024) / 4);
    // 2. W -> Wt (bf16, transposed)
    k_transpose_w<<<dim3(96, 32), dim3(32, 8), 0, stream>>>(W, Wt, 1024, 3072);
    // 3. qkv = x*W + b  (M=8192, N=3072, K=1024) -> Qb | Kb | Vt(transposed)
    k_g128qkv<<<dim3(24, 64), 256, 0, stream>>>(xb, 1024, Wt, 1024, Qb, Vt, bias, 1024);

    const float scale = 0.03125f;  // 1/sqrt(1024)
    // 4. P_unnorm = exp(Q*K^T*scale), partial row sums (M=4096, N=4096, K=1024)
    //    256x128 tiles, 256 thr, grid (32,16,2) = 1024 blocks -> 2 blocks/CU
    k_scores<<<dim3(32, 16, 2), 256, 0, stream>>>(
        Qb, Qb + 8388608, Pcat, part, 1024, scale, 4194304, 4194304, 16777216);
    // 5. rinv = 1/rowsum
    k_rinv<<<32, 256, 0, stream>>>(part, rinv, 8192);
    // 6. out = (P_unnorm * V) * rinv  (M=4096, N=1024, K=4096, z=2)
    k_pv256<<<dim3(8, 16, 2), 512, 0, stream>>>(
        Pcat, Vt, out, rinv, 4096, 16777216, 4194304, 4194304);
}

// Round 17
// 257.736 us; speedup vs baseline: 1.0287x; 1.0287x over previous
//
#include <hip/hip_runtime.h>
#include <hip/hip_bf16.h>

// ---------- types & helpers ----------
typedef __attribute__((ext_vector_type(4))) float  f32x4;
typedef __attribute__((ext_vector_type(8))) __bf16 bf16x8;
typedef __attribute__((ext_vector_type(8))) unsigned short u16x8;

typedef const __attribute__((address_space(1))) void gas_void;
typedef __attribute__((address_space(3))) void las_void;

__device__ __forceinline__ unsigned short f2bf(float x) {
    unsigned u = __builtin_bit_cast(unsigned, x);
    u += 0x7fffu + ((u >> 16) & 1u);          // round-to-nearest-even
    return (unsigned short)(u >> 16);
}
__device__ __forceinline__ float bf2f(unsigned short h) {
    unsigned u = ((unsigned)h) << 16;
    return __builtin_bit_cast(float, u);
}
__device__ __forceinline__ void gload_lds16(const void* g, void* l) {
    __builtin_amdgcn_global_load_lds((gas_void*)g, (las_void*)l, 16, 0, 0);
}

#define WAITVM(N) asm volatile("s_waitcnt vmcnt(" #N ")" ::: "memory")
#define BAR() do { __builtin_amdgcn_s_barrier(); __builtin_amdgcn_sched_barrier(0); } while (0)

// ---------- kernel 1: fp32 -> bf16 convert (vectorized) ----------
__global__ void k_f32_to_bf16(const float* __restrict__ in,
                              unsigned short* __restrict__ out, int n4) {
    int i = blockIdx.x * blockDim.x + threadIdx.x;
    if (i < n4) {
        float4 v = ((const float4*)in)[i];
        ushort4 o;
        o.x = f2bf(v.x); o.y = f2bf(v.y); o.z = f2bf(v.z); o.w = f2bf(v.w);
        ((ushort4*)out)[i] = o;
    }
}

// ---------- kernel 2: W [K=1024][N=3072] fp32 -> Wt [N][K] bf16 ----------
__global__ void k_transpose_w(const float* __restrict__ W,
                              unsigned short* __restrict__ Wt,
                              int K, int N) {
    __shared__ unsigned short tile[32][33];
    int n0 = blockIdx.x * 32, k0 = blockIdx.y * 32;
    int tx = threadIdx.x, ty = threadIdx.y;   // 32 x 8
#pragma unroll
    for (int i = 0; i < 4; i++) {
        int kk = ty + i * 8;
        tile[kk][tx] = f2bf(W[(size_t)(k0 + kk) * N + n0 + tx]);
    }
    __syncthreads();
#pragma unroll
    for (int i = 0; i < 4; i++) {
        int nn = ty + i * 8;
        Wt[(size_t)(n0 + nn) * K + k0 + tx] = tile[tx][nn];
    }
}

// ============================================================================
// GEMM1: 128x128 tile, BK=64, 4 waves, 256 thr, 2-phase (R9/R10-verified).
// L2-hot operands; ~1.3 PF measured.
// ============================================================================
__global__ __launch_bounds__(256, 2) void k_g128qkv(
        const unsigned short* __restrict__ A, int lda,
        const unsigned short* __restrict__ Bt, int ldb,
        unsigned short* __restrict__ C,
        unsigned short* __restrict__ Vt,
        const float* __restrict__ bias, int K) {
    __shared__ __align__(16) unsigned short As[2][8192];   // 128x64
    __shared__ __align__(16) unsigned short Bs[2][8192];   // 128x64

    const int nwg  = gridDim.x * gridDim.y;
    const int flat = blockIdx.y * gridDim.x + blockIdx.x;
    const int swzb = (flat & 7) * (nwg >> 3) + (flat >> 3);
    const int m0   = (swzb / gridDim.x) * 128;
    const int n0   = (swzb % gridDim.x) * 128;

    const int tid  = threadIdx.x;
    const int lane = tid & 63;
    const int wid  = tid >> 6;      // 0..3
    const int wr   = wid >> 1;
    const int wc   = wid & 1;
    const int l15  = lane & 15;
    const int l4   = lane >> 4;

    f32x4 acc[4][4] = {};

    const int srow = tid >> 3;                              // 0..31
    const int kel  = (((lane & 7) ^ (lane >> 3)) << 3);
    const int c0 = (l4 << 4) ^ ((l15 & 7) << 4);
    const int c1 = (64 + (l4 << 4)) ^ ((l15 & 7) << 4);

    auto stA = [&](int b, int g, int kt) {
        gload_lds16(A + (size_t)(m0 + g * 32 + srow) * lda + kt * 64 + kel,
                    (char*)As + b * 16384 + g * 4096 + (wid << 10));
    };
    auto stB = [&](int b, int g, int kt) {
        gload_lds16(Bt + (size_t)(n0 + g * 32 + srow) * ldb + kt * 64 + kel,
                    (char*)Bs + b * 16384 + g * 4096 + (wid << 10));
    };

#define MM(I, J, X, Y) \
    acc[I][J] = __builtin_amdgcn_mfma_f32_16x16x32_bf16((X), (Y), acc[I][J], 0, 0, 0)

    const int NT = K >> 6;
    stA(0, 0, 0); stA(0, 1, 0); stA(0, 2, 0); stA(0, 3, 0);
    stB(0, 0, 0); stB(0, 1, 0); stB(0, 2, 0); stB(0, 3, 0);

    for (int t = 0; t < NT; t++) {
        const int cur = t & 1, nxt = cur ^ 1;
        const char* Ab = (const char*)As + cur * 16384;
        const char* Bb = (const char*)Bs + cur * 16384;
        const bool hn = (t + 1 < NT);

        bf16x8 af[4], bq[4];

        if (hn) {
            stA(nxt, 0, t + 1); stA(nxt, 1, t + 1); stA(nxt, 2, t + 1); stA(nxt, 3, t + 1);
            WAITVM(4);
        } else {
            WAITVM(0);
        }
        BAR();
#pragma unroll
        for (int mf = 0; mf < 4; mf++)
            af[mf] = *(const bf16x8*)(Ab + (wr * 64 + mf * 16 + l15) * 128 + c0);
#pragma unroll
        for (int nf = 0; nf < 4; nf++)
            bq[nf] = *(const bf16x8*)(Bb + (wc * 64 + nf * 16 + l15) * 128 + c0);
        __builtin_amdgcn_s_setprio(1);
#pragma unroll
        for (int mf = 0; mf < 4; mf++)
#pragma unroll
        for (int nf = 0; nf < 4; nf++)
            MM(mf, nf, af[mf], bq[nf]);
        __builtin_amdgcn_s_setprio(0);

        if (hn) {
            stB(nxt, 0, t + 1); stB(nxt, 1, t + 1); stB(nxt, 2, t + 1); stB(nxt, 3, t + 1);
        }
#pragma unroll
        for (int mf = 0; mf < 4; mf++)
            af[mf] = *(const bf16x8*)(Ab + (wr * 64 + mf * 16 + l15) * 128 + c1);
#pragma unroll
        for (int nf = 0; nf < 4; nf++)
            bq[nf] = *(const bf16x8*)(Bb + (wc * 64 + nf * 16 + l15) * 128 + c1);
        __builtin_amdgcn_s_setprio(1);
#pragma unroll
        for (int mf = 0; mf < 4; mf++)
#pragma unroll
        for (int nf = 0; nf < 4; nf++)
            MM(mf, nf, af[mf], bq[nf]);
        __builtin_amdgcn_s_setprio(0);
        BAR();
    }
#undef MM

#pragma unroll
    for (int mf = 0; mf < 4; mf++) {
        const int row = m0 + wr * 64 + mf * 16 + l4 * 4;
#pragma unroll
        for (int nf = 0; nf < 4; nf++) {
            const int col = n0 + wc * 64 + nf * 16 + l15;
            const f32x4 av = acc[mf][nf];
            const float bv = bias[col];
            const int lc = col & 1023;
            if (col < 2048) {
#pragma unroll
                for (int r = 0; r < 4; r++)
                    C[(size_t)(col >> 10) * 8388608 +
                      (size_t)(row + r) * 1024 + lc] = f2bf(av[r] + bv);
            } else {
                const int b = row >> 12, s = row & 4095;
                ushort4 o;
                o.x = f2bf(av[0] + bv); o.y = f2bf(av[1] + bv);
                o.z = f2bf(av[2] + bv); o.w = f2bf(av[3] + bv);
                *(ushort4*)&Vt[(size_t)b * 4194304 + (size_t)lc * 4096 + s] = o;
            }
        }
    }
}

// ============================================================================
// SCORES: 256x256, BK=64, 8 waves (2M x 4N), 512 thr, 2-phase + deep-slack
// staging (R12-best, reproduced R15): whole tile t+1 (8 instrs) issued at P1
// top, gate WAITVM(8) retires exactly tile t (FIFO; outstanding=16).
// Epilogue: P = exp(s*scale) unnormalized + deterministic per-row partials.
// ============================================================================
__global__ __launch_bounds__(512, 2) void k_scores(
        const unsigned short* __restrict__ A,
        const unsigned short* __restrict__ Bt,
        unsigned short* __restrict__ C,
        float* __restrict__ part,
        int K, float scale, long sA, long sB, long sC) {
    __shared__ __align__(16) unsigned short As[2][16384];
    __shared__ __align__(16) unsigned short Bs[2][16384];

    const int z = blockIdx.z;
    A  += (size_t)z * sA;
    Bt += (size_t)z * sB;

    const int nwg  = gridDim.x * gridDim.y;
    const int flat = blockIdx.y * gridDim.x + blockIdx.x;
    const int swzb = (flat & 7) * (nwg >> 3) + (flat >> 3);
    const int m0   = (swzb / gridDim.x) * 256;
    const int n0   = (swzb % gridDim.x) * 256;

    const int tid  = threadIdx.x;
    const int lane = tid & 63;
    const int wid  = tid >> 6;      // 0..7
    const int wm   = wid >> 2;      // 0..1
    const int wn   = wid & 3;       // 0..3
    const int l15  = lane & 15;
    const int l4   = lane >> 4;     // 0..3

    f32x4 acc[8][4] = {};           // 128 AGPR

    const int srow = tid >> 3;                              // 0..63
    const int kel  = (((lane & 7) ^ (lane >> 3)) << 3);
    const int c0 = ((l4 << 4)) ^ ((l15 & 7) << 4);
    const int c1 = (64 + (l4 << 4)) ^ ((l15 & 7) << 4);

    auto stageA = [&](int b, int h, int kt) {
#pragma unroll
        for (int c = 0; c < 2; c++) {
            const int r = h * 128 + c * 64 + srow;
            gload_lds16(A + (size_t)(m0 + r) * 1024 + kt * 64 + kel,
                        (char*)As + b * 32768 + h * 16384 + c * 8192 + (wid << 10));
        }
    };
    auto stageB = [&](int b, int h, int kt) {
#pragma unroll
        for (int c = 0; c < 2; c++) {
            const int r = h * 128 + c * 64 + srow;
            gload_lds16(Bt + (size_t)(n0 + r) * 1024 + kt * 64 + kel,
                        (char*)Bs + b * 32768 + h * 16384 + c * 8192 + (wid << 10));
        }
    };

#define MM(I, J, X, Y) \
    acc[I][J] = __builtin_amdgcn_mfma_f32_16x16x32_bf16((X), (Y), acc[I][J], 0, 0, 0)

    const int NT = K >> 6;
    stageA(0, 0, 0); stageB(0, 0, 0); stageA(0, 1, 0); stageB(0, 1, 0);

    for (int t = 0; t < NT; t++) {
        const int cur = t & 1, nxt = cur ^ 1;
        const char* Ab = (const char*)As + cur * 32768;
        const char* Bb = (const char*)Bs + cur * 32768;

        // ---------- P1: stage FULL tile t+1, deep gate ----------
        if (t + 1 < NT) {
            stageA(nxt, 0, t + 1); stageB(nxt, 0, t + 1);
            stageA(nxt, 1, t + 1); stageB(nxt, 1, t + 1);
            WAITVM(8);     // outstanding 16 -> retires exactly tile t's 8
        } else {
            WAITVM(0);
        }
        BAR();

        bf16x8 bfrg[2][2][2];
#pragma unroll
        for (int qn = 0; qn < 2; qn++)
#pragma unroll
        for (int nf = 0; nf < 2; nf++) {
            const int rb = (wn * 64 + qn * 32 + nf * 16 + l15) * 128;
            bfrg[qn][nf][0] = *(const bf16x8*)(Bb + rb + c0);
            bfrg[qn][nf][1] = *(const bf16x8*)(Bb + rb + c1);
        }
        {
            bf16x8 af[4][2];
#pragma unroll
            for (int mf = 0; mf < 4; mf++) {
                const int ra = (wm * 128 + 0 * 64 + mf * 16 + l15) * 128;
                af[mf][0] = *(const bf16x8*)(Ab + ra + c0);
                af[mf][1] = *(const bf16x8*)(Ab + ra + c1);
            }
            __builtin_amdgcn_s_setprio(1);
#pragma unroll
            for (int mf = 0; mf < 4; mf++)
#pragma unroll
            for (int qn = 0; qn < 2; qn++)
#pragma unroll
            for (int nf = 0; nf < 2; nf++) {
                MM(mf, qn * 2 + nf, af[mf][0], bfrg[qn][nf][0]);
                MM(mf, qn * 2 + nf, af[mf][1], bfrg[qn][nf][1]);
            }
            __builtin_amdgcn_s_setprio(0);
        }

        // ---------- P2 (no staging) ----------
        {
            bf16x8 af[4][2];
#pragma unroll
            for (int mf = 0; mf < 4; mf++) {
                const int ra = (wm * 128 + 1 * 64 + mf * 16 + l15) * 128;
                af[mf][0] = *(const bf16x8*)(Ab + ra + c0);
                af[mf][1] = *(const bf16x8*)(Ab + ra + c1);
            }
            __builtin_amdgcn_s_setprio(1);
#pragma unroll
            for (int mf = 0; mf < 4; mf++)
#pragma unroll
            for (int qn = 0; qn < 2; qn++)
#pragma unroll
            for (int nf = 0; nf < 2; nf++) {
                MM(4 + mf, qn * 2 + nf, af[mf][0], bfrg[qn][nf][0]);
                MM(4 + mf, qn * 2 + nf, af[mf][1], bfrg[qn][nf][1]);
            }
            __builtin_amdgcn_s_setprio(0);
        }
        __builtin_amdgcn_s_barrier();
        __builtin_amdgcn_sched_barrier(0);
    }
#undef MM

    // ---- epilogue: exp + write P_unnorm + per-row partial sums ----
    const int cb4 = ((n0 >> 8) << 2) + wn;     // partial-sum slot 0..63
#pragma unroll
    for (int qm = 0; qm < 2; qm++)
#pragma unroll
    for (int mf = 0; mf < 4; mf++) {
        const int row = m0 + wm * 128 + qm * 64 + mf * 16 + l4 * 4;
        float rs[4] = {0.f, 0.f, 0.f, 0.f};
#pragma unroll
        for (int qn = 0; qn < 2; qn++)
#pragma unroll
        for (int nf = 0; nf < 2; nf++) {
            const int col = n0 + wn * 64 + qn * 32 + nf * 16 + l15;
            const f32x4 av = acc[qm * 4 + mf][qn * 2 + nf];
#pragma unroll
            for (int r = 0; r < 4; r++) {
                const float e = __expf(av[r] * scale);
                rs[r] += e;
                C[(size_t)z * sC + (size_t)(row + r) * 4096 + col] = f2bf(e);
            }
        }
#pragma unroll
        for (int r = 0; r < 4; r++) {
#pragma unroll
            for (int o = 1; o < 16; o <<= 1)
                rs[r] += __shfl_xor(rs[r], o);
        }
        if (l15 == 0) {
#pragma unroll
            for (int r = 0; r < 4; r++)
                part[((size_t)z * 4096 + row + r) * 64 + cb4] = rs[r];
        }
    }
}

// ---------- reduce 64 partials -> rinv = 1/rowsum ----------
__global__ __launch_bounds__(256) void k_rinv(const float* __restrict__ part,
                                              float* __restrict__ rinv, int nrows) {
    int row = blockIdx.x * blockDim.x + threadIdx.x;
    if (row < nrows) {
        const float* p = part + (size_t)row * 64;
        float s = 0.f;
#pragma unroll
        for (int i = 0; i < 16; i++) {
            f32x4 v = *(const f32x4*)(p + i * 4);
            s += v[0] + v[1] + v[2] + v[3];
        }
        rinv[row] = 1.0f / s;
    }
}

// ============================================================================
// PV: 256x128 tile, BK=64, 8 waves (2M x 4N), 512 thr, 2-phase + deep-slack
// staging (R12-best, reproduced R15): all 6 stage instrs of tile t+1 at P1
// top, gate WAITVM(6) (outstanding 12 -> retires exactly tile t).
// Epilogue: out = acc * rinv[row].
// ============================================================================
__global__ __launch_bounds__(512, 2) void k_pv256(
        const unsigned short* __restrict__ A,
        const unsigned short* __restrict__ Bt,
        float* __restrict__ C,
        const float* __restrict__ rinv,
        int K, long sA, long sB, long sC) {
    __shared__ __align__(16) unsigned short As[2][16384];   // 256x64
    __shared__ __align__(16) unsigned short Bs[2][8192];    // 128x64

    const int z = blockIdx.z;
    A  += (size_t)z * sA;
    Bt += (size_t)z * sB;

    const int nwg  = gridDim.x * gridDim.y;      // 128
    const int flat = blockIdx.y * gridDim.x + blockIdx.x;
    const int swzb = (flat & 7) * (nwg >> 3) + (flat >> 3);
    const int m0   = (swzb / gridDim.x) * 256;
    const int n0   = (swzb % gridDim.x) * 128;

    const int tid  = threadIdx.x;
    const int lane = tid & 63;
    const int wid  = tid >> 6;
    const int wm   = wid >> 2;
    const int wn   = wid & 3;
    const int l15  = lane & 15;
    const int l4   = lane >> 4;

    f32x4 acc[8][2] = {};

    const int srow = tid >> 3;
    const int kel  = (((lane & 7) ^ (lane >> 3)) << 3);
    const int c0 = ((l4 << 4)) ^ ((l15 & 7) << 4);
    const int c1 = (64 + (l4 << 4)) ^ ((l15 & 7) << 4);

    auto stageA1 = [&](int b, int a, int kt) {
        const int r = a * 64 + srow;
        gload_lds16(A + (size_t)(m0 + r) * 4096 + kt * 64 + kel,
                    (char*)As + b * 32768 + a * 8192 + (wid << 10));
    };
    auto stageB1 = [&](int b, int c, int kt) {
        const int r = c * 64 + srow;
        gload_lds16(Bt + (size_t)(n0 + r) * 4096 + kt * 64 + kel,
                    (char*)Bs + b * 16384 + c * 8192 + (wid << 10));
    };

#define MM(I, J, X, Y) \
    acc[I][J] = __builtin_amdgcn_mfma_f32_16x16x32_bf16((X), (Y), acc[I][J], 0, 0, 0)

    const int NT = K >> 6;
    stageA1(0, 0, 0); stageA1(0, 1, 0); stageA1(0, 2, 0); stageA1(0, 3, 0);
    stageB1(0, 0, 0); stageB1(0, 1, 0);

    for (int t = 0; t < NT; t++) {
        const int cur = t & 1, nxt = cur ^ 1;
        const char* Ab = (const char*)As + cur * 32768;
        const char* Bb = (const char*)Bs + cur * 16384;

        // ---------- P1: stage FULL tile t+1, deep gate ----------
        if (t + 1 < NT) {
            stageA1(nxt, 0, t + 1); stageA1(nxt, 1, t + 1);
            stageA1(nxt, 2, t + 1); stageA1(nxt, 3, t + 1);
            stageB1(nxt, 0, t + 1); stageB1(nxt, 1, t + 1);
            WAITVM(6);     // outstanding 12 -> retires exactly tile t's 6
        } else {
            WAITVM(0);
        }
        BAR();

        bf16x8 bfrg[2][2];
#pragma unroll
        for (int nf = 0; nf < 2; nf++) {
            const int rb = (wn * 32 + nf * 16 + l15) * 128;
            bfrg[nf][0] = *(const bf16x8*)(Bb + rb + c0);
            bfrg[nf][1] = *(const bf16x8*)(Bb + rb + c1);
        }
        {
            bf16x8 af[4][2];
#pragma unroll
            for (int mf = 0; mf < 4; mf++) {
                const int ra = (wm * 128 + 0 * 64 + mf * 16 + l15) * 128;
                af[mf][0] = *(const bf16x8*)(Ab + ra + c0);
                af[mf][1] = *(const bf16x8*)(Ab + ra + c1);
            }
            __builtin_amdgcn_s_setprio(1);
#pragma unroll
            for (int mf = 0; mf < 4; mf++)
#pragma unroll
            for (int nf = 0; nf < 2; nf++) {
                MM(mf, nf, af[mf][0], bfrg[nf][0]);
                MM(mf, nf, af[mf][1], bfrg[nf][1]);
            }
            __builtin_amdgcn_s_setprio(0);
        }

        // ---------- P2 (no staging) ----------
        {
            bf16x8 af[4][2];
#pragma unroll
            for (int mf = 0; mf < 4; mf++) {
                const int ra = (wm * 128 + 1 * 64 + mf * 16 + l15) * 128;
                af[mf][0] = *(const bf16x8*)(Ab + ra + c0);
                af[mf][1] = *(const bf16x8*)(Ab + ra + c1);
            }
            __builtin_amdgcn_s_setprio(1);
#pragma unroll
            for (int mf = 0; mf < 4; mf++)
#pragma unroll
            for (int nf = 0; nf < 2; nf++) {
                MM(4 + mf, nf, af[mf][0], bfrg[nf][0]);
                MM(4 + mf, nf, af[mf][1], bfrg[nf][1]);
            }
            __builtin_amdgcn_s_setprio(0);
        }
        __builtin_amdgcn_s_barrier();
        __builtin_amdgcn_sched_barrier(0);
    }
#undef MM

    // epilogue: normalize by rinv[row] and store fp32
#pragma unroll
    for (int qm = 0; qm < 2; qm++)
#pragma unroll
    for (int mf = 0; mf < 4; mf++) {
        const int row = m0 + wm * 128 + qm * 64 + mf * 16 + l4 * 4;
        const f32x4 riv = *(const f32x4*)&rinv[(size_t)z * 4096 + row];
#pragma unroll
        for (int nf = 0; nf < 2; nf++) {
            const int col = n0 + wn * 32 + nf * 16 + l15;
            const f32x4 av = acc[qm * 4 + mf][nf];
#pragma unroll
            for (int r = 0; r < 4; r++)
                C[(size_t)z * sC + (size_t)(row + r) * 1024 + col] = av[r] * riv[r];
        }
    }
}

// ---------- launch ----------
extern "C" void kernel_launch(void* const* d_in, const int* in_sizes, int n_in,
                              void* d_out, int out_size, void* d_ws, size_t ws_size,
                              hipStream_t stream) {
    const float* x    = (const float*)d_in[0];   // [2,4096,1024]
    const float* W    = (const float*)d_in[1];   // [1024,3072]
    const float* bias = (const float*)d_in[2];   // [3072]
    float* out        = (float*)d_out;           // [2,4096,1024]

    // ws (MB): Qb@0(16) Kb@16(16) Vt@32(16) xb@48(16) Wt@64(6)
    //          Pcat@48(64, overlays dead xb/Wt) part@112(4) rinv@116(32KB)
    char* ws = (char*)d_ws;
    unsigned short* Qb   = (unsigned short*)(ws);
    unsigned short* Vt   = (unsigned short*)(ws + 33554432);
    unsigned short* xb   = (unsigned short*)(ws + 50331648);
    unsigned short* Wt   = (unsigned short*)(ws + 67108864);
    unsigned short* Pcat = (unsigned short*)(ws + 50331648);
    float*          part = (float*)(ws + 117440512);
    float*          rinv = (float*)(ws + 121634816);

    // 1. x -> bf16
    k_f32_to_bf16<<<8192, 256, 0, stream>>>(x, xb, (8192 * 1024) / 4);
    // 2. W -> Wt (bf16, transposed)
    k_transpose_w<<<dim3(96, 32), dim3(32, 8), 0, stream>>>(W, Wt, 1024, 3072);
    // 3. qkv = x*W + b  (M=8192, N=3072, K=1024) -> Qb | Kb | Vt(transposed)
    k_g128qkv<<<dim3(24, 64), 256, 0, stream>>>(xb, 1024, Wt, 1024, Qb, Vt, bias, 1024);

    const float scale = 0.03125f;  // 1/sqrt(1024)
    // 4. P_unnorm = exp(Q*K^T*scale), partial row sums (M=N=4096, K=1024, z=2)
    k_scores<<<dim3(16, 16, 2), 512, 0, stream>>>(
        Qb, Qb + 8388608, Pcat, part, 1024, scale, 4194304, 4194304, 16777216);
    // 5. rinv = 1/rowsum
    k_rinv<<<32, 256, 0, stream>>>(part, rinv, 8192);
    // 6. out = (P_unnorm * V) * rinv  (M=4096, N=1024, K=4096, z=2)
    k_pv256<<<dim3(8, 16, 2), 512, 0, stream>>>(
        Pcat, Vt, out, rinv, 4096, 16777216, 4194304, 4194304);
}